// Round 5
// baseline (625.918 us; speedup 1.0000x reference)
//
#include <hip/hip_runtime.h>
#include <cmath>

// SparseCausalAttentionBlock on MI355X (gfx950).
// Round 10: LDS-bandwidth attack. R7/R8/R9 (three different K-loop structures)
// all flat at ~4050 cyc/CU per K-tile vs 1242 MFMA floor -> limiter is the
// CU-shared LDS pipe: 128 ds_read_b128 x ~12cyc = 1536 cyc/tile (m134) +
// staging writes, identical in all three variants (64x64 wave tiles). Fix:
// wave tile 64x128 (acc[4][8], ~210 VGPR, 2 waves/SIMD): per-CU ds_read drops
// 128->96 inst/tile, reads:MFMA 0.5->0.375. Block 128x512x32 kept, 8 waves,
// 512 thr, triple-buffered, per-tile issue = 4xB + 1xA-half, steady vmcnt(5).
// LN epilogue per-fm (row stats live within one fm) -> no big stash; output
// processed as two 64-col halves via the proven stride-68 cw path.
// Attention / conv unchanged.

typedef unsigned short u16;
typedef unsigned int u32;
typedef __bf16 bf16_t;
typedef bf16_t bf16x8 __attribute__((ext_vector_type(8)));
typedef float f32x4 __attribute__((ext_vector_type(4)));

#define DEV __device__ __forceinline__
#define MFMA16(a, b, c) __builtin_amdgcn_mfma_f32_16x16x32_bf16(a, b, c, 0, 0, 0)
#define SBAR() __builtin_amdgcn_sched_barrier(0)

DEV u16 f2b(float f) {  // fp32 -> bf16 RNE
  u32 u = __float_as_uint(f);
  u32 r = u + 0x7fffu + ((u >> 16) & 1u);
  return (u16)(r >> 16);
}
DEV float b2f(u16 b) { return __uint_as_float(((u32)b) << 16); }

DEV float gelu_erf(float x) {
  // gelu(x) = 0.5 x (1 + erf(x/sqrt2)); erf via A&S 7.1.26 (max err 1.5e-7)
  float y = x * 0.70710678118654752f;
  float ay = fabsf(y);
  float t = __builtin_amdgcn_rcpf(1.0f + 0.3275911f * ay);
  float p = t * (0.254829592f +
            t * (-0.284496736f +
            t * (1.421413741f +
            t * (-1.453152027f + t * 1.061405429f))));
  float e = 1.0f - p * __expf(-y * y);
  float erfv = (y < 0.f) ? -e : e;
  return 0.5f * x * (1.0f + erfv);
}

DEV void g2l16(const void* g, void* l) {
  // async global->LDS, 16B/lane; LDS dest = wave-uniform base + lane*16
  __builtin_amdgcn_global_load_lds((const __attribute__((address_space(1))) void*)g,
                                   (__attribute__((address_space(3))) void*)l,
                                   16, 0, 0);
}

// ---------------- fp32 -> bf16 converter (2048 elems / block) ---------------
__global__ __launch_bounds__(256) void conv1(const float* __restrict__ s,
                                             u16* __restrict__ d) {
  size_t idx = ((size_t)blockIdx.x * 256 + threadIdx.x) * 8;
  float4 a = *(const float4*)(s + idx);
  float4 b = *(const float4*)(s + idx + 4);
  float v[8] = {a.x, a.y, a.z, a.w, b.x, b.y, b.z, b.w};
  union { u16 q[8]; uint4 u; } pk;
#pragma unroll
  for (int i = 0; i < 8; ++i) pk.q[i] = f2b(v[i]);
  *(uint4*)(d + idx) = pk.u;
}

// ---- bf16 MFMA GEMM 128x512x32, 512 thr, wave tile 64x128 ------------------
// C = A @ B^T (+bias)(+res)(gelu | LN). 8 waves (2M x 4N), acc[4][8].
// LDS: A pair-slots p*16384 (128 rows x 128B = K-tiles 2p,2p+1);
//      B slots 49152 + s*32768 (512 rows x 64B). Epilogue reuses LDS.
template <bool GELU, bool RES32, bool RESB, bool LN, bool OUT32, bool OUTB>
__global__ __launch_bounds__(512, 2) void gemmV(
    const u16* __restrict__ A, const u16* __restrict__ B,
    const float* __restrict__ bias, const float* __restrict__ res32,
    const u16* __restrict__ resb, const float* __restrict__ lnG,
    const float* __restrict__ lnB, float* __restrict__ out32,
    u16* __restrict__ outb, int M, int N, int K) {
  __shared__ __align__(16) char smem[147456];
  const int tid = threadIdx.x;
  const int lane = tid & 63, wv = tid >> 6;
  const int wm = wv >> 2, wn = wv & 3;
  const int lrow = lane & 15, quad = lane >> 4;

  // bijective XCD-chunked block swizzle (m204 form)
  int idx = blockIdx.x;
  {
    const int nwg = gridDim.x;
    if (nwg >= 8) {
      const int q = nwg >> 3, r = nwg & 7;
      const int xcd = idx & 7, rk = idx >> 3;
      idx = (xcd < r ? xcd * (q + 1) : r * (q + 1) + (xcd - r) * q) + rk;
    }
  }
  const int nx = N >> 9;
  const int m0 = (idx / nx) * 128, n0 = (idx % nx) * 512;

  // ---- LDS read offsets (swizzled; same involutions as the write side) ----
  // A: row stride 128B; phys_chunk(3b) = (half*4 + quad) ^ (row&7), row&7=lrow&7
  const int c0q = quad ^ (lrow & 3);
  const int hbit = (lrow >> 2) & 1;
  int aOffE[4], aOffO[4], bOff[8];
#pragma unroll
  for (int m = 0; m < 4; ++m) {
    const int rb = (wm * 64 + m * 16 + lrow) * 128;
    aOffE[m] = rb + (c0q + hbit * 4) * 16;
    aOffO[m] = rb + (c0q + (1 - hbit) * 4) * 16;
  }
  // B: row stride 64B; phys_chunk(2b) = quad ^ ((row>>1)&3), (row>>1)&3=(lrow>>1)&3
#pragma unroll
  for (int n = 0; n < 8; ++n)
    bOff[n] = (wn * 128 + n * 16 + lrow) * 64 + ((quad ^ ((lrow >> 1) & 3)) * 16);

  // ---- staging (512 thr, pre-swizzled global src, linear LDS dest) ----
  // B call covers 128 rows (8KB): row = roff + tid>>2, phys chunk = tid&3,
  //   logical chunk = (tid&3)^((tid>>3)&3)  [(row>>1)&3 == (tid>>3)&3, roff%128==0]
  const int lB = (tid & 3) ^ ((tid >> 3) & 3);
  const int lA = (tid & 7) ^ ((tid >> 3) & 7);
  const char* BsrcT = (const char*)B + (((size_t)(n0 + (tid >> 2)) * K + lB * 8) << 1);
  const size_t bRow128 = ((size_t)K << 1) * 128;
  // A call covers 64 rows (8KB): row = hf*64 + tid>>3, phys chunk = tid&7
  const char* Asrc0 = (const char*)A + (((size_t)(m0 + (tid >> 3)) * K + lA * 8) << 1);
  const char* Asrc1 = Asrc0 + (((size_t)K << 1) * 64);
  const int sdst = tid * 16;

  const int nt = K >> 5, ntp = nt >> 1;

  auto stageB = [&](int kt, int slot) {
    const char* g = BsrcT + ((size_t)kt << 6);
    char* d = smem + 49152 + slot * 32768 + sdst;
#pragma unroll
    for (int r = 0; r < 4; ++r) g2l16(g + r * bRow128, d + r * 8192);
  };
  auto stageA = [&](int pr, int hf, int slot) {
    g2l16((hf ? Asrc1 : Asrc0) + ((size_t)pr << 7),
          smem + slot * 16384 + hf * 8192 + sdst);
  };

  f32x4 acc[4][8];
  f32x4 zero4 = {0.f, 0.f, 0.f, 0.f};
#pragma unroll
  for (int a = 0; a < 4; ++a)
#pragma unroll
    for (int b = 0; b < 8; ++b) acc[a][b] = zero4;

  // prologue: A pair0(2), B0(4), B1(4), A pair1(2); keep newest 6 in flight
  stageA(0, 0, 0); stageA(0, 1, 0);
  stageB(0, 0);
  stageB(1, 1);
  stageA(1, 0, 1); stageA(1, 1, 1);
  SBAR();
  asm volatile("s_waitcnt vmcnt(6)" ::: "memory");
  asm volatile("s_barrier" ::: "memory");
  SBAR();

  int sB0 = 0, sB2 = 2, pA = 0, pA2 = 2;
  for (int tp = 0; tp < ntp; ++tp) {
#pragma unroll
    for (int half = 0; half < 2; ++half) {
      const int t = tp * 2 + half;
      const char* Ab = smem + pA * 16384;
      const char* Bb = smem + 49152 + sB0 * 32768;
      bf16x8 afr[4], bfr[8];
#pragma unroll
      for (int m = 0; m < 4; ++m)
        afr[m] = *(const bf16x8*)(Ab + (half ? aOffO[m] : aOffE[m]));
#pragma unroll
      for (int n = 0; n < 8; ++n)
        bfr[n] = *(const bf16x8*)(Bb + bOff[n]);
      // stage B(t+2) into slot (t+2)%3 and A pair(tp+2) half into (tp+2)%3
      const int ktB = (t + 2 < nt) ? t + 2 : nt - 1;   // tail: junk, never read
      stageB(ktB, sB2);
      const int p2 = (tp + 2 < ntp) ? tp + 2 : ntp - 1;
      stageA(p2, half, pA2);
      SBAR();
      asm volatile("s_waitcnt lgkmcnt(0)" ::: "memory");
      SBAR();
      __builtin_amdgcn_s_setprio(1);
#pragma unroll
      for (int m = 0; m < 4; ++m)
#pragma unroll
        for (int n = 0; n < 8; ++n)
          acc[m][n] = MFMA16(afr[m], bfr[n], acc[m][n]);
      __builtin_amdgcn_s_setprio(0);
      SBAR();
      // outstanding = prev tile's 5 + this tile's 5 -> land prev, keep 5
      asm volatile("s_waitcnt vmcnt(5)" ::: "memory");
      asm volatile("s_barrier" ::: "memory");
      SBAR();
      sB0 = (sB0 == 2) ? 0 : sB0 + 1;
      sB2 = (sB2 == 2) ? 0 : sB2 + 1;
    }
    pA = (pA == 2) ? 0 : pA + 1;
    pA2 = (pA2 == 2) ? 0 : pA2 + 1;
  }

  // drain remaining (junk) stages before reusing LDS
  asm volatile("s_waitcnt vmcnt(0)" ::: "memory");
  __syncthreads();

  // ---- epilogue: per-wave cw staging (16 rows x 68 f32), two 64-col halves
  float* cw = (float*)(smem + (size_t)wv * 4352);
  float* red = (float*)(smem + 131072);  // [128 rows][4 wn][2] f32 = 4KB
  const int row16 = lane >> 2;
  const int c0 = (lane & 3) * 16;

#pragma unroll
  for (int fm = 0; fm < 4; ++fm) {
    const int grow = m0 + wm * 64 + fm * 16 + row16;
    float vv[2][16];
    float s1 = 0.f, s2 = 0.f;
#pragma unroll
    for (int hf = 0; hf < 2; ++hf) {
      // scatter acc (C-layout: row=quad*4+r, col=fn*16+lrow) into cw
#pragma unroll
      for (int fn = 0; fn < 4; ++fn)
#pragma unroll
        for (int r = 0; r < 4; ++r)
          cw[(quad * 4 + r) * 68 + fn * 16 + lrow] = acc[fm][hf * 4 + fn][r];
      const int gcb = n0 + wn * 128 + hf * 64 + c0;
      const size_t gbase = (size_t)grow * N + gcb;
      const float* crp = &cw[row16 * 68 + c0];
      float v[16];
#pragma unroll
      for (int t = 0; t < 4; ++t) {
        f32x4 q = *(const f32x4*)(crp + t * 4);
        float4 b4 = *(const float4*)(bias + gcb + t * 4);
        v[t * 4 + 0] = q[0] + b4.x;
        v[t * 4 + 1] = q[1] + b4.y;
        v[t * 4 + 2] = q[2] + b4.z;
        v[t * 4 + 3] = q[3] + b4.w;
      }
      if (RES32) {
#pragma unroll
        for (int t = 0; t < 4; ++t) {
          float4 rr = *(const float4*)(res32 + gbase + t * 4);
          v[t * 4 + 0] += rr.x; v[t * 4 + 1] += rr.y;
          v[t * 4 + 2] += rr.z; v[t * 4 + 3] += rr.w;
        }
      }
      if (RESB) {
#pragma unroll
        for (int t = 0; t < 2; ++t) {
          union { u16 q[8]; uint4 u; } rb;
          rb.u = *(const uint4*)(resb + gbase + t * 8);
#pragma unroll
          for (int j = 0; j < 8; ++j) v[t * 8 + j] += b2f(rb.q[j]);
        }
      }
      if (GELU) {
#pragma unroll
        for (int e = 0; e < 16; ++e) v[e] = gelu_erf(v[e]);
      }
      if (LN) {
#pragma unroll
        for (int e = 0; e < 16; ++e) {
          s1 += v[e];
          s2 += v[e] * v[e];
          vv[hf][e] = v[e];
        }
      } else {
        if (OUT32) {
#pragma unroll
          for (int t = 0; t < 4; ++t) {
            float4 w4 = {v[t * 4 + 0], v[t * 4 + 1], v[t * 4 + 2], v[t * 4 + 3]};
            *(float4*)(out32 + gbase + t * 4) = w4;
          }
        }
        if (OUTB) {
#pragma unroll
          for (int t = 0; t < 2; ++t) {
            union { u16 q[8]; uint4 u; } pk;
#pragma unroll
            for (int j = 0; j < 8; ++j) pk.q[j] = f2b(v[t * 8 + j]);
            *(uint4*)(outb + gbase + t * 8) = pk.u;
          }
        }
      }
    }
    if (LN) {
      // reduce lane&3 (each covers 32 of the wave's 128 cols) -> red[row][wn]
      s1 += __shfl_xor(s1, 1); s2 += __shfl_xor(s2, 1);
      s1 += __shfl_xor(s1, 2); s2 += __shfl_xor(s2, 2);
      const int lr = wm * 64 + fm * 16 + row16;
      if ((lane & 3) == 0) {
        red[lr * 8 + wn * 2 + 0] = s1;
        red[lr * 8 + wn * 2 + 1] = s2;
      }
      __syncthreads();  // red rows unique per fm -> no cross-fm collision
      const float* rp = &red[lr * 8];
      f32x4 qa = *(const f32x4*)rp;
      f32x4 qb = *(const f32x4*)(rp + 4);
      const float t1 = qa[0] + qa[2] + qb[0] + qb[2];
      const float t2 = qa[1] + qa[3] + qb[1] + qb[3];
      const float mean = t1 * (1.0f / 512.0f);
      const float var = t2 * (1.0f / 512.0f) - mean * mean;
      const float rs = rsqrtf(var + 1e-5f);
#pragma unroll
      for (int hf = 0; hf < 2; ++hf) {
        const int gcb = n0 + wn * 128 + hf * 64 + c0;
        const size_t gbase = (size_t)grow * N + gcb;
        float o[16];
#pragma unroll
        for (int t = 0; t < 4; ++t) {
          float4 gg = *(const float4*)(lnG + gcb + t * 4);
          float4 bb = *(const float4*)(lnB + gcb + t * 4);
          o[t * 4 + 0] = (vv[hf][t * 4 + 0] - mean) * rs * gg.x + bb.x;
          o[t * 4 + 1] = (vv[hf][t * 4 + 1] - mean) * rs * gg.y + bb.y;
          o[t * 4 + 2] = (vv[hf][t * 4 + 2] - mean) * rs * gg.z + bb.z;
          o[t * 4 + 3] = (vv[hf][t * 4 + 3] - mean) * rs * gg.w + bb.w;
        }
        if (OUT32) {
#pragma unroll
          for (int t = 0; t < 4; ++t) {
            float4 w4 = {o[t * 4 + 0], o[t * 4 + 1], o[t * 4 + 2], o[t * 4 + 3]};
            *(float4*)(out32 + gbase + t * 4) = w4;
          }
        }
        if (OUTB) {
#pragma unroll
          for (int t = 0; t < 2; ++t) {
            union { u16 q[8]; uint4 u; } pk;
#pragma unroll
            for (int j = 0; j < 8; ++j) pk.q[j] = f2b(o[t * 8 + j]);
            *(uint4*)(outb + gbase + t * 8) = pk.u;
          }
        }
      }
    }
  }
}

// ---------------- MFMA local windowed causal attention (window=64) ----------
__global__ __launch_bounds__(256) void local_attn_mfma(const u16* __restrict__ qkv,
                                                       u16* __restrict__ outb) {
  __shared__ u16 vt[64][152];      // V^T: [dim][key 0..143, pad->152]
  __shared__ u16 pb[4][16][104];   // per-wave P: [query][key 0..95 pad 104]
  const int tid = threadIdx.x;
  const int lane = tid & 63, w = tid >> 6;
  const int c = lane & 15, quad = lane >> 4;
  const int bx = blockIdx.x;
  const int qb = bx & 7, h = (bx >> 3) & 7, bb = bx >> 6;
  const int i0 = qb * 64;
  const int hc = h * 64;
  const size_t rbase = (size_t)bb * 512;

  {
    int r = tid >> 1;              // 0..127
    int d0 = (tid & 1) * 32;
    int key = i0 - 64 + r;
    if (key < 0) key = 0;
    if (key > 511) key = 511;
    const u16* Vr = qkv + (rbase + key) * 1536 + 1024 + hc + d0;
#pragma unroll
    for (int g = 0; g < 4; ++g) {
      union { u16 q[8]; uint4 u; } vv;
      vv.u = *(const uint4*)(Vr + g * 8);
#pragma unroll
      for (int j = 0; j < 8; ++j) vt[d0 + g * 8 + j][r] = vv.q[j];
    }
    if (tid < 128) {               // keys 128..143
      int r2 = 128 + (tid >> 3);
      int d2 = (tid & 7) * 8;
      int key2 = i0 - 64 + r2;
      if (key2 < 0) key2 = 0;
      if (key2 > 511) key2 = 511;
      const u16* Vr2 = qkv + (rbase + key2) * 1536 + 1024 + hc + d2;
      union { u16 q[8]; uint4 u; } vv2;
      vv2.u = *(const uint4*)Vr2;
#pragma unroll
      for (int j = 0; j < 8; ++j) vt[d2 + j][r2] = vv2.q[j];
    }
  }
  __syncthreads();

  const int i0w = i0 + 16 * w;
  const int kg0 = i0w - 64;

  bf16x8 qf0, qf1;
  {
    const u16* Qr = qkv + (rbase + i0w + c) * 1536 + hc + quad * 8;
    qf0 = *(const bf16x8*)Qr;
    qf1 = *(const bf16x8*)(Qr + 32);
  }

  f32x4 s[5];
#pragma unroll
  for (int kb = 0; kb < 5; ++kb) {
    int key = kg0 + kb * 16 + c; if (key < 0) key = 0;
    const u16* Kr = qkv + (rbase + key) * 1536 + 512 + hc + quad * 8;
    bf16x8 k0 = *(const bf16x8*)Kr;
    bf16x8 k1 = *(const bf16x8*)(Kr + 32);
    f32x4 z = {0.f, 0.f, 0.f, 0.f};
    z = __builtin_amdgcn_mfma_f32_16x16x32_bf16(qf0, k0, z, 0, 0, 0);
    s[kb] = __builtin_amdgcn_mfma_f32_16x16x32_bf16(qf1, k1, z, 0, 0, 0);
  }

  float mx[4];
#pragma unroll
  for (int r = 0; r < 4; ++r) {
    int row = quad * 4 + r;
    float m = -1e30f;
#pragma unroll
    for (int kb = 0; kb < 5; ++kb) {
      float v = s[kb][r] * 0.125f;
      int key = kg0 + kb * 16 + c;
      bool ok = key >= 0;
      if (kb == 0) ok = ok && (c >= row);
      if (kb == 4) ok = ok && (c <= row);
      v = ok ? v : -1e30f;
      s[kb][r] = v;
      m = fmaxf(m, v);
    }
    mx[r] = m;
  }
#pragma unroll
  for (int o = 1; o <= 8; o <<= 1)
#pragma unroll
    for (int r = 0; r < 4; ++r) mx[r] = fmaxf(mx[r], __shfl_xor(mx[r], o));

  float l[4] = {0.f, 0.f, 0.f, 0.f};
#pragma unroll
  for (int kb = 0; kb < 5; ++kb)
#pragma unroll
    for (int r = 0; r < 4; ++r) {
      u16 pq = f2b(__expf(s[kb][r] - mx[r]));
      l[r] += b2f(pq);
      pb[w][quad * 4 + r][kb * 16 + c] = pq;
    }
#pragma unroll
  for (int r = 0; r < 4; ++r) pb[w][quad * 4 + r][80 + c] = 0;
#pragma unroll
  for (int o = 1; o <= 8; o <<= 1)
#pragma unroll
    for (int r = 0; r < 4; ++r) l[r] += __shfl_xor(l[r], o);
  float inv[4];
#pragma unroll
  for (int r = 0; r < 4; ++r) inv[r] = 1.f / l[r];

  f32x4 o4[4];
#pragma unroll
  for (int nb = 0; nb < 4; ++nb) o4[nb] = f32x4{0.f, 0.f, 0.f, 0.f};
#pragma unroll
  for (int kt = 0; kt < 3; ++kt) {
    bf16x8 pa = *(const bf16x8*)&pb[w][c][kt * 32 + quad * 8];
#pragma unroll
    for (int nb = 0; nb < 4; ++nb) {
      bf16x8 vb = *(const bf16x8*)&vt[nb * 16 + c][16 * w + kt * 32 + quad * 8];
      o4[nb] = __builtin_amdgcn_mfma_f32_16x16x32_bf16(pa, vb, o4[nb], 0, 0, 0);
    }
  }
#pragma unroll
  for (int nb = 0; nb < 4; ++nb)
#pragma unroll
    for (int r = 0; r < 4; ++r) {
      int seq = i0w + quad * 4 + r;
      outb[(rbase + seq) * 512 + hc + nb * 16 + c] = f2b(o4[nb][r] * inv[r]);
    }
}

// ---------------- MFMA global attention over 32 anchors ---------------------
__global__ __launch_bounds__(256) void global_attn_mfma(const u16* __restrict__ qg,
                                                        const u16* __restrict__ kvg,
                                                        u16* __restrict__ outb) {
  __shared__ u16 vt[64][40];
  __shared__ u16 pb[4][16][40];
  const int tid = threadIdx.x;
  const int lane = tid & 63, w = tid >> 6;
  const int c = lane & 15, quad = lane >> 4;
  const int bx = blockIdx.x;
  const int qb = bx & 7, h = (bx >> 3) & 7, bb = bx >> 6;
  const int i0 = qb * 64;
  const int hc = h * 64;
  const size_t rbase = (size_t)bb * 512;

  {
    int r = tid >> 3;
    int d0 = (tid & 7) * 8;
    const u16* Vr = kvg + ((size_t)bb * 32 + r) * 1024 + 512 + hc + d0;
    union { u16 q[8]; uint4 u; } vv;
    vv.u = *(const uint4*)Vr;
#pragma unroll
    for (int j = 0; j < 8; ++j) vt[d0 + j][r] = vv.q[j];
  }
  __syncthreads();

  const int i0w = i0 + 16 * w;
  bf16x8 qf0, qf1;
  {
    const u16* Qr = qg + (rbase + i0w + c) * 512 + hc + quad * 8;
    qf0 = *(const bf16x8*)Qr;
    qf1 = *(const bf16x8*)(Qr + 32);
  }
  f32x4 s[2];
#pragma unroll
  for (int kb = 0; kb < 2; ++kb) {
    const u16* Kr = kvg + ((size_t)bb * 32 + kb * 16 + c) * 1024 + hc + quad * 8;
    bf16x8 k0 = *(const bf16x8*)Kr;
    bf16x8 k1 = *(const bf16x8*)(Kr + 32);
    f32x4 z = {0.f, 0.f, 0.f, 0.f};
    z = __builtin_amdgcn_mfma_f32_16x16x32_bf16(qf0, k0, z, 0, 0, 0);
    s[kb] = __builtin_amdgcn_mfma_f32_16x16x32_bf16(qf1, k1, z, 0, 0, 0);
  }
  float mx[4];
#pragma unroll
  for (int r = 0; r < 4; ++r)
    mx[r] = fmaxf(s[0][r] * 0.125f, s[1][r] * 0.125f);
#pragma unroll
  for (int o = 1; o <= 8; o <<= 1)
#pragma unroll
    for (int r = 0; r < 4; ++r) mx[r] = fmaxf(mx[r], __shfl_xor(mx[r], o));
  float l[4] = {0.f, 0.f, 0.f, 0.f};
#pragma unroll
  for (int kb = 0; kb < 2; ++kb)
#pragma unroll
    for (int r = 0; r < 4; ++r) {
      u16 pq = f2b(__expf(s[kb][r] * 0.125f - mx[r]));
      l[r] += b2f(pq);
      pb[w][quad * 4 + r][kb * 16 + c] = pq;
    }
#pragma unroll
  for (int o = 1; o <= 8; o <<= 1)
#pragma unroll
    for (int r = 0; r < 4; ++r) l[r] += __shfl_xor(l[r], o);
  float inv[4];
#pragma unroll
  for (int r = 0; r < 4; ++r) inv[r] = 1.f / l[r];

  f32x4 o4[4];
#pragma unroll
  for (int nb = 0; nb < 4; ++nb) o4[nb] = f32x4{0.f, 0.f, 0.f, 0.f};
  bf16x8 pa = *(const bf16x8*)&pb[w][c][quad * 8];
#pragma unroll
  for (int nb = 0; nb < 4; ++nb) {
    bf16x8 vb = *(const bf16x8*)&vt[nb * 16 + c][quad * 8];
    o4[nb] = __builtin_amdgcn_mfma_f32_16x16x32_bf16(pa, vb, o4[nb], 0, 0, 0);
  }
#pragma unroll
  for (int nb = 0; nb < 4; ++nb)
#pragma unroll
    for (int r = 0; r < 4; ++r) {
      int seq = i0w + quad * 4 + r;
      outb[(rbase + seq) * 512 + hc + nb * 16 + c] = f2b(o4[nb][r] * inv[r]);
    }
}

// ---------------- driver -----------------------------------------------------
extern "C" void kernel_launch(void* const* d_in, const int* in_sizes, int n_in,
                              void* d_out, int out_size, void* d_ws, size_t ws_size,
                              hipStream_t stream) {
  const float* x      = (const float*)d_in[0];
  const float* anchors= (const float*)d_in[1];
  const float* lw_in  = (const float*)d_in[2];
  const float* lb_in  = (const float*)d_in[3];
  const float* lw_out = (const float*)d_in[4];
  const float* lb_out = (const float*)d_in[5];
  const float* gw_in  = (const float*)d_in[6];
  const float* gb_in  = (const float*)d_in[7];
  const float* gw_out = (const float*)d_in[8];
  const float* gb_out = (const float*)d_in[9];
  const float* w1     = (const float*)d_in[10];
  const float* b1     = (const float*)d_in[11];
  const float* w2     = (const float*)d_in[12];
  const float* b2     = (const float*)d_in[13];
  const float* g1     = (const float*)d_in[14];
  const float* be1    = (const float*)d_in[15];
  const float* g2     = (const float*)d_in[16];
  const float* be2    = (const float*)d_in[17];
  (void)in_sizes; (void)n_in; (void)out_size;
  float* out = (float*)d_out;

  char* ws = (char*)d_ws;
  size_t o = 0;
  auto nxt = [&](size_t bytes) { char* p = ws + o; o += bytes; return p; };
  u16* lwib = (u16*)nxt((size_t)1536 * 512 * 2);
  u16* lwob = (u16*)nxt((size_t)512 * 512 * 2);
  u16* gwib = (u16*)nxt((size_t)1536 * 512 * 2);
  u16* gwob = (u16*)nxt((size_t)512 * 512 * 2);
  u16* w1b  = (u16*)nxt((size_t)2048 * 512 * 2);
  u16* w2b  = (u16*)nxt((size_t)512 * 2048 * 2);
  u16* ab   = (u16*)nxt((size_t)2048 * 512 * 2);
  u16* kvgb = (u16*)nxt((size_t)2048 * 1024 * 2);
  const size_t wbytes = o;

  int nc = 1;
  while (wbytes + (size_t)(32768 / nc) * 6144 > ws_size && nc < 32) nc <<= 1;
  const int Mc = 32768 / nc;
  const int nBat = Mc / 512;
  const int mbW = Mc >> 7;   // 128-row tiles
  u16* BIGb = (u16*)nxt((size_t)Mc * 4096);
  u16* Pb   = (u16*)nxt((size_t)Mc * 1024);
  u16* Qb   = (u16*)nxt((size_t)Mc * 1024);
  u16* Sb   = BIGb + (size_t)Mc * 1536;

  conv1<<<384, 256, 0, stream>>>(lw_in, lwib);
  conv1<<<128, 256, 0, stream>>>(lw_out, lwob);
  conv1<<<384, 256, 0, stream>>>(gw_in, gwib);
  conv1<<<128, 256, 0, stream>>>(gw_out, gwob);
  conv1<<<512, 256, 0, stream>>>(w1, w1b);
  conv1<<<512, 256, 0, stream>>>(w2, w2b);
  conv1<<<512, 256, 0, stream>>>(anchors, ab);
  // anchors KV: [2048 x 1024] = anchors @ gw_in[512:1536]^T
  gemmV<false, false, false, false, false, true><<<16 * 2, 512, 0, stream>>>(
      ab, gwib + 512 * 512, gb_in + 512, nullptr, nullptr, nullptr, nullptr,
      nullptr, kvgb, 2048, 1024, 512);

  for (int ck = 0; ck < nc; ++ck) {
    const size_t r0 = (size_t)ck * Mc;
    const float* xck = x + r0 * 512;
    conv1<<<Mc / 4, 256, 0, stream>>>(xck, Pb);
    gemmV<false, false, false, false, false, true><<<mbW * 3, 512, 0, stream>>>(
        Pb, lwib, lb_in, nullptr, nullptr, nullptr, nullptr,
        nullptr, BIGb, Mc, 1536, 512);
    local_attn_mfma<<<nBat * 64, 256, 0, stream>>>(BIGb, Sb);
    gemmV<false, true, false, false, false, true><<<mbW, 512, 0, stream>>>(
        Sb, lwob, lb_out, xck, nullptr, nullptr, nullptr,
        nullptr, Qb, Mc, 512, 512);
    gemmV<false, false, false, false, false, true><<<mbW, 512, 0, stream>>>(
        Qb, gwib, gb_in, nullptr, nullptr, nullptr, nullptr,
        nullptr, Pb, Mc, 512, 512);
    global_attn_mfma<<<nBat * 64, 256, 0, stream>>>(Pb, kvgb + (r0 / 512) * 32 * 1024, Sb);
    // proj3 + residual + LN1 fused -> Qb (res=Qb aliasing safe: per-block
    // reads precede writes; blocks own disjoint rows)
    gemmV<false, false, true, true, false, true><<<mbW, 512, 0, stream>>>(
        Sb, gwob, gb_out, nullptr, Qb, g1, be1,
        nullptr, Qb, Mc, 512, 512);
    gemmV<true, false, false, false, false, true><<<mbW * 4, 512, 0, stream>>>(
        Qb, w1b, b1, nullptr, nullptr, nullptr, nullptr,
        nullptr, BIGb, Mc, 2048, 512);
    // FFN2 + residual + LN2 fused -> final f32 out
    gemmV<false, false, true, true, true, false><<<mbW, 512, 0, stream>>>(
        BIGb, w2b, b2, nullptr, Qb, g2, be2,
        out + r0 * 512, nullptr, Mc, 512, 2048);
  }
}